// Round 11
// baseline (130.852 us; speedup 1.0000x reference)
//
#include <hip/hip_runtime.h>
#include <math.h>

#define HW_TOT (480*640)     // 307200 pixels per image
#define NQ (HW_TOT/4)        // 76800 float4-quads per image
#define NBATCH 4
#define NB 128               // bins
#define NGAP (NB+1)          // gaps between sorted bins (below/above included)
#define SBX 75               // stats blocks per batch: 75*256*4 quads == NQ
#define EPSV 1e-10f
#define INF_BITS 0x7F800000u

// ---- helpers ---------------------------------------------------------------
__device__ __forceinline__ int nzbytes(unsigned x) {
  return ((x & 0xFFu) != 0) + ((x & 0xFF00u) != 0) +
         ((x & 0xFF0000u) != 0) + ((x >> 24) != 0);
}

// Per-block mask-dtype sniff: wave 0 samples the first 1024 bytes.
// byte-bool (~973 nonzero) vs float32 (~486) vs int32 (~243); threshold 768.
__device__ __forceinline__ void sniff_mask(const void* mask, int tid, int* smode) {
  if (tid < 64) {
    const uint4* m16 = (const uint4*)mask;
    uint4 w = m16[tid];
    int c = nzbytes(w.x) + nzbytes(w.y) + nzbytes(w.z) + nzbytes(w.w);
#pragma unroll
    for (int off = 32; off > 0; off >>= 1) c += __shfl_down(c, off);
    if (tid == 0) *smode = (c >= 768) ? 0 : 1;
  }
}

__device__ __forceinline__ void mask4(const void* mask, int e, int mode, bool v[4]) {
  if (mode == 0) {
    unsigned mw = *(const unsigned*)((const unsigned char*)mask + e);
    v[0] = (mw & 0xFFu) != 0;        v[1] = ((mw >> 8) & 0xFFu) != 0;
    v[2] = ((mw >> 16) & 0xFFu) != 0; v[3] = (mw >> 24) != 0;
  } else {
    int4 mi = *(const int4*)((const int*)mask + e);
    v[0] = mi.x != 0; v[1] = mi.y != 0; v[2] = mi.z != 0; v[3] = mi.w != 0;
  }
}

// ---- kernel 1: stats partials (+ fused bin normalize/sort in bx==0 blocks) --
__global__ __launch_bounds__(256) void k_stats(const float* __restrict__ pred,
                                               const float* __restrict__ targ,
                                               const void* __restrict__ mask,
                                               const float* __restrict__ bins,
                                               float* __restrict__ bn,      // [NBATCH][NB] sorted normalized
                                               float4* __restrict__ pacc,   // [NBATCH*SBX]
                                               float* __restrict__ ptmax) { // [NBATCH*SBX]
  const int b = blockIdx.y, bx = blockIdx.x, tid = threadIdx.x;
  __shared__ int smode;
  sniff_mask(mask, tid, &smode);
  __syncthreads();
  const int mode = smode;
  const int base = b * HW_TOT;

  float cnt = 0.f, sd = 0.f, sd2 = 0.f, sl2 = 0.f, tm = 0.f;
#pragma unroll
  for (int k = 0; k < 4; ++k) {
    const int q = bx * 1024 + k * 256 + tid;     // coalesced per iteration
    const int e = base + q * 4;
    const float4 t4 = *(const float4*)(targ + e);
    const float4 p4 = *(const float4*)(pred + e);
    bool v[4];
    mask4(mask, e, mode, v);
    const float t[4] = {t4.x, t4.y, t4.z, t4.w};
    const float p[4] = {p4.x, p4.y, p4.z, p4.w};
#pragma unroll
    for (int j = 0; j < 4; ++j) {
      const float m = v[j] ? 1.f : 0.f;
      const float d = logf(p[j] + EPSV) - logf(t[j] + EPSV);
      cnt += m;
      sd  += m * d;
      sd2 += m * d * d;
      const float er = p[j] - t[j];
      sl2 += m * er * er;
      if (v[j]) tm = fmaxf(tm, t[j]);
    }
  }
#pragma unroll
  for (int off = 32; off > 0; off >>= 1) {
    cnt += __shfl_down(cnt, off);
    sd  += __shfl_down(sd,  off);
    sd2 += __shfl_down(sd2, off);
    sl2 += __shfl_down(sl2, off);
    tm   = fmaxf(tm, __shfl_down(tm, off));
  }
  __shared__ float red[4][5];
  const int wave = tid >> 6, lane = tid & 63;
  if (lane == 0) {
    red[wave][0] = cnt; red[wave][1] = sd; red[wave][2] = sd2;
    red[wave][3] = sl2; red[wave][4] = tm;
  }
  __syncthreads();
  if (tid == 0) {
    float C = 0, S = 0, S2 = 0, L = 0, T = 0;
#pragma unroll
    for (int w = 0; w < 4; ++w) {
      C += red[w][0]; S += red[w][1]; S2 += red[w][2]; L += red[w][3];
      T = fmaxf(T, red[w][4]);
    }
    pacc[b * SBX + bx] = make_float4(C, S, S2, L);
    ptmax[b * SBX + bx] = T;
  }

  // ---- fused setup tail: block bx==0 normalizes + bitonic-sorts batch b bins
  if (bx == 0) {
    __shared__ float sb[NB];
    __shared__ float sred2[64];
    if (tid < NB) sb[tid] = bins[b * NB + tid];
    __syncthreads();
    if (tid < 64) sred2[tid] = fmaxf(sb[tid], sb[tid + 64]);
    __syncthreads();
    for (int s = 32; s > 0; s >>= 1) {
      if (tid < s) sred2[tid] = fmaxf(sred2[tid], sred2[tid + s]);
      __syncthreads();
    }
    const float bmax = sred2[0];
    __syncthreads();
    if (tid < NB) sb[tid] = bins[b * NB + tid] / bmax;  // faithful f32 division
    __syncthreads();
    for (int k = 2; k <= NB; k <<= 1) {
      for (int jj = k >> 1; jj > 0; jj >>= 1) {
        const int ixj = tid ^ jj;
        if (tid < NB && ixj > tid) {
          const float a = sb[tid], c = sb[ixj];
          const bool up = ((tid & k) == 0);
          if (up ? (a > c) : (a < c)) { sb[tid] = c; sb[ixj] = a; }
        }
        __syncthreads();
      }
    }
    if (tid < NB) bn[b * NB + tid] = sb[tid];
  }
}

// ---- kernel 2: chamfer partials. grid (nbx, NBATCH), 256 threads. ----------
__global__ __launch_bounds__(256) void k_chamfer(const float* __restrict__ targ,
                                                 const void* __restrict__ mask,
                                                 const float* __restrict__ bn,
                                                 const float* __restrict__ ptmax,
                                                 float* __restrict__ pcsum,      // [NBATCH*nbx]
                                                 unsigned* __restrict__ pgmin,   // [NBATCH*nbx][NGAP]
                                                 unsigned* __restrict__ pgmax,
                                                 int nbx) {
  const int b = blockIdx.y, bx = blockIdx.x, tid = threadIdx.x;
  __shared__ int smode;
  __shared__ float sbn[NB];
  __shared__ unsigned sgmin[NGAP], sgmax[NGAP];
  __shared__ float stmax;

  sniff_mask(mask, tid, &smode);
  if (tid < NB) sbn[tid] = bn[b * NB + tid];
  if (tid < NGAP) { sgmin[tid] = INF_BITS; sgmax[tid] = 0u; }
  if (tid >= 128 && tid < 192) {               // wave 2: merge SBX tmax partials
    const int l = tid - 128;
    float v = (l < SBX) ? ptmax[b * SBX + l] : 0.f;
    if (l + 64 < SBX) v = fmaxf(v, ptmax[b * SBX + l + 64]);
#pragma unroll
    for (int off = 32; off > 0; off >>= 1) v = fmaxf(v, __shfl_down(v, off));
    if (l == 0) stmax = v;
  }
  __syncthreads();
  const int mode = smode;
  const float tmax = stmax;
  const int base = b * HW_TOT;

  float csum = 0.f;
  for (int q = bx * 256 + tid; q < NQ; q += nbx * 256) {
    const int e = base + q * 4;
    const float4 t4 = *(const float4*)(targ + e);
    bool v[4];
    mask4(mask, e, mode, v);
    const float t[4] = {t4.x, t4.y, t4.z, t4.w};
#pragma unroll
    for (int k = 0; k < 4; ++k) {
      if (v[k]) {
        const float tn = t[k] / tmax;          // faithful f32 division
        int pos = 0;                           // count of bins < tn
#pragma unroll
        for (int s = 64; s > 0; s >>= 1) {
          const int np = pos + s;
          if (np <= NB && sbn[np - 1] < tn) pos = np;
        }
        if (sbn[NB - 1] < tn) pos = NB;
        const float c0 = sbn[pos > 0 ? pos - 1 : 0];
        const float c1 = sbn[pos < NB ? pos : NB - 1];
        const float d0 = tn - c0, d1 = tn - c1;
        csum += fminf(d0 * d0, d1 * d1);
        const unsigned tb = __float_as_uint(tn);  // tn >= 0: uint order == float order
        atomicMin(&sgmin[pos], tb);
        atomicMax(&sgmax[pos], tb);
      }
    }
  }
#pragma unroll
  for (int off = 32; off > 0; off >>= 1) csum += __shfl_down(csum, off);
  __shared__ float cred[4];
  const int wave = tid >> 6, lane = tid & 63;
  if (lane == 0) cred[wave] = csum;
  __syncthreads();
  const int slot = b * nbx + bx;
  if (tid == 0) pcsum[slot] = cred[0] + cred[1] + cred[2] + cred[3];
  if (tid < NGAP) {
    pgmin[slot * NGAP + tid] = sgmin[tid];
    pgmax[slot * NGAP + tid] = sgmax[tid];
  }
}

// ---- kernel 3: merge partials + b->t gap scan + combine. 1 block, 512 thr. -
__global__ __launch_bounds__(512) void k_final(const float* __restrict__ bn,
                                               const float4* __restrict__ pacc,
                                               const float* __restrict__ pcsum,
                                               const unsigned* __restrict__ pgmin,
                                               const unsigned* __restrict__ pgmax,
                                               int nbx,
                                               float* __restrict__ out) {
  const int tid = threadIdx.x;
  __shared__ double wacc[8][4];
  __shared__ unsigned mgmin[NBATCH][NGAP], mgmax[NBATCH][NGAP];
  __shared__ double dcs[NBATCH];
  __shared__ float sred[512];

  // A: merge stats partials (300 float4 -> doubles)
  double a0 = 0, a1 = 0, a2 = 0, a3 = 0;
  if (tid < NBATCH * SBX) {
    const float4 p = pacc[tid];
    a0 = p.x; a1 = p.y; a2 = p.z; a3 = p.w;
  }
#pragma unroll
  for (int off = 32; off > 0; off >>= 1) {
    a0 += __shfl_down(a0, off); a1 += __shfl_down(a1, off);
    a2 += __shfl_down(a2, off); a3 += __shfl_down(a3, off);
  }
  if ((tid & 63) == 0) {
    wacc[tid >> 6][0] = a0; wacc[tid >> 6][1] = a1;
    wacc[tid >> 6][2] = a2; wacc[tid >> 6][3] = a3;
  }
  // B: merge per-block gap min/max (coalesced over g for each k)
  for (int o = tid; o < NBATCH * NGAP; o += 512) {
    const int b = o / NGAP, g = o - b * NGAP;
    unsigned mn = INF_BITS, mx = 0u;
    for (int k = 0; k < nbx; ++k) {
      mn = min(mn, pgmin[(b * nbx + k) * NGAP + g]);
      mx = max(mx, pgmax[(b * nbx + k) * NGAP + g]);
    }
    mgmin[b][g] = mn; mgmax[b][g] = mx;
  }
  // C: merge chamfer csums
  if (tid < NBATCH) {
    double cs = 0.0;
    for (int k = 0; k < nbx; ++k) cs += (double)pcsum[tid * nbx + k];
    dcs[tid] = cs;
  }
  __syncthreads();

  // D: b->t via gap scan (bin never falls strictly inside a gap's pixel range)
  const int b = tid >> 7, j = tid & 127;
  const float bnj = bn[b * NB + j];
  float md = INFINITY;
  for (int g = 0; g < NGAP; ++g) {
    const float gmn = __uint_as_float(mgmin[b][g]);
    const float gmx = __uint_as_float(mgmax[b][g]);
    const float d = fmaxf(fmaxf(gmn - bnj, bnj - gmx), 0.0f);
    md = fminf(md, d * d);
  }
  sred[tid] = isfinite(md) ? md : 0.0f;   // rows with min==inf contribute 0
  __syncthreads();
  for (int s = 64; s > 0; s >>= 1) {
    if (j < s) sred[tid] += sred[tid + s];
    __syncthreads();
  }
  if (tid == 0) {
    double n = 0, sdv = 0, sd2v = 0, sl2v = 0;
#pragma unroll
    for (int w = 0; w < 8; ++w) {
      n += wacc[w][0]; sdv += wacc[w][1]; sd2v += wacc[w][2]; sl2v += wacc[w][3];
    }
    const double mean_d = sdv / n, mean_d2 = sd2v / n;
    const double silog = 10.0 * sqrt(mean_d2 - 0.85 * mean_d * mean_d);
    const double l2 = sqrt(sl2v / n);
    double ch = 0.0;
    for (int bb = 0; bb < NBATCH; ++bb) ch += dcs[bb] + (double)sred[bb * 128];
    ch /= (double)NBATCH;
    out[0] = (float)(l2 + silog + ch);
  }
}

extern "C" void kernel_launch(void* const* d_in, const int* in_sizes, int n_in,
                              void* d_out, int out_size, void* d_ws, size_t ws_size,
                              hipStream_t stream) {
  const float* pred = (const float*)d_in[0];
  const float* targ = (const float*)d_in[1];
  const float* bins = (const float*)d_in[2];
  const void*  mask = d_in[3];
  float* out = (float*)d_out;

  // Workspace layout:
  char* w = (char*)d_ws;
  float*  bn    = (float*)w;                    // 2048 B
  float4* pacc  = (float4*)(w + 2048);          // 4800 B -> 6848
  float*  ptmax = (float*)(w + 6848);           // 1200 B -> 8048 (pad to 8064)
  const size_t hdr = 8064;
  auto need = [&](size_t nb) {
    return hdr + 4 * nb * sizeof(float) + 2 * 4 * nb * NGAP * sizeof(unsigned);
  };
  // chamfer blocks per batch: 128 -> 512 blocks total = 2 blocks/CU (8 waves/CU)
  // to hide the dependent-LDS binary-search latency. Fallback for small ws.
  int nbx = 128;
  if (ws_size < need(128)) nbx = (ws_size >= need(16)) ? 16 : 4;
  float*    pcsum = (float*)(w + hdr);
  unsigned* pgmin = (unsigned*)(w + hdr + 4 * nbx * sizeof(float));
  unsigned* pgmax = pgmin + 4 * (size_t)nbx * NGAP;

  k_stats<<<dim3(SBX, NBATCH), dim3(256), 0, stream>>>(pred, targ, mask, bins,
                                                       bn, pacc, ptmax);
  k_chamfer<<<dim3(nbx, NBATCH), dim3(256), 0, stream>>>(targ, mask, bn, ptmax,
                                                         pcsum, pgmin, pgmax, nbx);
  k_final<<<dim3(1), dim3(512), 0, stream>>>(bn, pacc, pcsum, pgmin, pgmax, nbx, out);
}

// Round 12
// 98.300 us; speedup vs baseline: 1.3311x; 1.3311x over previous
//
#include <hip/hip_runtime.h>
#include <math.h>

#define HW_TOT (480*640)     // 307200 pixels per image
#define NQ (HW_TOT/4)        // 76800 float4-quads per image
#define NBATCH 4
#define NB 128               // bins
#define NGAP (NB+1)          // gaps between sorted bins (below/above included)
#define SBX 75               // stats blocks per batch: 75*256*4 quads == NQ
#define EPSV 1e-10f
#define INF_BITS 0x7F800000u

// ---- helpers ---------------------------------------------------------------
__device__ __forceinline__ int nzbytes(unsigned x) {
  return ((x & 0xFFu) != 0) + ((x & 0xFF00u) != 0) +
         ((x & 0xFF0000u) != 0) + ((x >> 24) != 0);
}

// Per-block mask-dtype sniff: wave 0 samples the first 1024 bytes.
// byte-bool (~973 nonzero) vs float32 (~486) vs int32 (~243); threshold 768.
__device__ __forceinline__ void sniff_mask(const void* mask, int tid, int* smode) {
  if (tid < 64) {
    const uint4* m16 = (const uint4*)mask;
    uint4 w = m16[tid];
    int c = nzbytes(w.x) + nzbytes(w.y) + nzbytes(w.z) + nzbytes(w.w);
#pragma unroll
    for (int off = 32; off > 0; off >>= 1) c += __shfl_down(c, off);
    if (tid == 0) *smode = (c >= 768) ? 0 : 1;
  }
}

__device__ __forceinline__ void mask4(const void* mask, int e, int mode, bool v[4]) {
  if (mode == 0) {
    unsigned mw = *(const unsigned*)((const unsigned char*)mask + e);
    v[0] = (mw & 0xFFu) != 0;        v[1] = ((mw >> 8) & 0xFFu) != 0;
    v[2] = ((mw >> 16) & 0xFFu) != 0; v[3] = (mw >> 24) != 0;
  } else {
    int4 mi = *(const int4*)((const int*)mask + e);
    v[0] = mi.x != 0; v[1] = mi.y != 0; v[2] = mi.z != 0; v[3] = mi.w != 0;
  }
}

// ---- kernel 1: stats partials (+ fused bin normalize/sort in bx==0 blocks) --
__global__ __launch_bounds__(256) void k_stats(const float* __restrict__ pred,
                                               const float* __restrict__ targ,
                                               const void* __restrict__ mask,
                                               const float* __restrict__ bins,
                                               float* __restrict__ bn,      // [NBATCH][NB] sorted normalized
                                               float4* __restrict__ pacc,   // [NBATCH*SBX]
                                               float* __restrict__ ptmax) { // [NBATCH*SBX]
  const int b = blockIdx.y, bx = blockIdx.x, tid = threadIdx.x;
  __shared__ int smode;
  sniff_mask(mask, tid, &smode);
  __syncthreads();
  const int mode = smode;
  const int base = b * HW_TOT;

  float cnt = 0.f, sd = 0.f, sd2 = 0.f, sl2 = 0.f, tm = 0.f;
#pragma unroll
  for (int k = 0; k < 4; ++k) {
    const int q = bx * 1024 + k * 256 + tid;     // coalesced per iteration
    const int e = base + q * 4;
    const float4 t4 = *(const float4*)(targ + e);
    const float4 p4 = *(const float4*)(pred + e);
    bool v[4];
    mask4(mask, e, mode, v);
    const float t[4] = {t4.x, t4.y, t4.z, t4.w};
    const float p[4] = {p4.x, p4.y, p4.z, p4.w};
#pragma unroll
    for (int j = 0; j < 4; ++j) {
      const float m = v[j] ? 1.f : 0.f;
      const float d = logf(p[j] + EPSV) - logf(t[j] + EPSV);
      cnt += m;
      sd  += m * d;
      sd2 += m * d * d;
      const float er = p[j] - t[j];
      sl2 += m * er * er;
      if (v[j]) tm = fmaxf(tm, t[j]);
    }
  }
#pragma unroll
  for (int off = 32; off > 0; off >>= 1) {
    cnt += __shfl_down(cnt, off);
    sd  += __shfl_down(sd,  off);
    sd2 += __shfl_down(sd2, off);
    sl2 += __shfl_down(sl2, off);
    tm   = fmaxf(tm, __shfl_down(tm, off));
  }
  __shared__ float red[4][5];
  const int wave = tid >> 6, lane = tid & 63;
  if (lane == 0) {
    red[wave][0] = cnt; red[wave][1] = sd; red[wave][2] = sd2;
    red[wave][3] = sl2; red[wave][4] = tm;
  }
  __syncthreads();
  if (tid == 0) {
    float C = 0, S = 0, S2 = 0, L = 0, T = 0;
#pragma unroll
    for (int w = 0; w < 4; ++w) {
      C += red[w][0]; S += red[w][1]; S2 += red[w][2]; L += red[w][3];
      T = fmaxf(T, red[w][4]);
    }
    pacc[b * SBX + bx] = make_float4(C, S, S2, L);
    ptmax[b * SBX + bx] = T;
  }

  // ---- fused setup tail: block bx==0 normalizes + bitonic-sorts batch b bins
  if (bx == 0) {
    __shared__ float sb[NB];
    __shared__ float sred2[64];
    if (tid < NB) sb[tid] = bins[b * NB + tid];
    __syncthreads();
    if (tid < 64) sred2[tid] = fmaxf(sb[tid], sb[tid + 64]);
    __syncthreads();
    for (int s = 32; s > 0; s >>= 1) {
      if (tid < s) sred2[tid] = fmaxf(sred2[tid], sred2[tid + s]);
      __syncthreads();
    }
    const float bmax = sred2[0];
    __syncthreads();
    if (tid < NB) sb[tid] = bins[b * NB + tid] / bmax;  // faithful f32 division
    __syncthreads();
    for (int k = 2; k <= NB; k <<= 1) {
      for (int jj = k >> 1; jj > 0; jj >>= 1) {
        const int ixj = tid ^ jj;
        if (tid < NB && ixj > tid) {
          const float a = sb[tid], c = sb[ixj];
          const bool up = ((tid & k) == 0);
          if (up ? (a > c) : (a < c)) { sb[tid] = c; sb[ixj] = a; }
        }
        __syncthreads();
      }
    }
    if (tid < NB) bn[b * NB + tid] = sb[tid];
  }
}

// ---- kernel 2: chamfer partials. grid (nbx, NBATCH), 256 threads. ----------
__global__ __launch_bounds__(256) void k_chamfer(const float* __restrict__ targ,
                                                 const void* __restrict__ mask,
                                                 const float* __restrict__ bn,
                                                 const float* __restrict__ ptmax,
                                                 float* __restrict__ pcsum,      // [NBATCH*nbx]
                                                 unsigned* __restrict__ pgmin,   // [NBATCH*nbx][NGAP]
                                                 unsigned* __restrict__ pgmax,
                                                 int nbx) {
  const int b = blockIdx.y, bx = blockIdx.x, tid = threadIdx.x;
  __shared__ int smode;
  __shared__ float sbn[NB];
  __shared__ unsigned sgmin[NGAP], sgmax[NGAP];
  __shared__ float stmax;

  sniff_mask(mask, tid, &smode);
  if (tid < NB) sbn[tid] = bn[b * NB + tid];
  if (tid < NGAP) { sgmin[tid] = INF_BITS; sgmax[tid] = 0u; }
  if (tid >= 128 && tid < 192) {               // wave 2: merge SBX tmax partials
    const int l = tid - 128;
    float v = (l < SBX) ? ptmax[b * SBX + l] : 0.f;
    if (l + 64 < SBX) v = fmaxf(v, ptmax[b * SBX + l + 64]);
#pragma unroll
    for (int off = 32; off > 0; off >>= 1) v = fmaxf(v, __shfl_down(v, off));
    if (l == 0) stmax = v;
  }
  __syncthreads();
  const int mode = smode;
  const float tmax = stmax;
  const int base = b * HW_TOT;

  float csum = 0.f;
  for (int q = bx * 256 + tid; q < NQ; q += nbx * 256) {
    const int e = base + q * 4;
    const float4 t4 = *(const float4*)(targ + e);
    bool v[4];
    mask4(mask, e, mode, v);
    const float t[4] = {t4.x, t4.y, t4.z, t4.w};
#pragma unroll
    for (int k = 0; k < 4; ++k) {
      if (v[k]) {
        const float tn = t[k] / tmax;          // faithful f32 division
        int pos = 0;                           // count of bins < tn
#pragma unroll
        for (int s = 64; s > 0; s >>= 1) {
          const int np = pos + s;
          if (np <= NB && sbn[np - 1] < tn) pos = np;
        }
        if (sbn[NB - 1] < tn) pos = NB;
        const float c0 = sbn[pos > 0 ? pos - 1 : 0];
        const float c1 = sbn[pos < NB ? pos : NB - 1];
        const float d0 = tn - c0, d1 = tn - c1;
        csum += fminf(d0 * d0, d1 * d1);
        const unsigned tb = __float_as_uint(tn);  // tn >= 0: uint order == float order
        atomicMin(&sgmin[pos], tb);
        atomicMax(&sgmax[pos], tb);
      }
    }
  }
#pragma unroll
  for (int off = 32; off > 0; off >>= 1) csum += __shfl_down(csum, off);
  __shared__ float cred[4];
  const int wave = tid >> 6, lane = tid & 63;
  if (lane == 0) cred[wave] = csum;
  __syncthreads();
  const int slot = b * nbx + bx;
  if (tid == 0) pcsum[slot] = cred[0] + cred[1] + cred[2] + cred[3];
  if (tid < NGAP) {
    pgmin[slot * NGAP + tid] = sgmin[tid];
    pgmax[slot * NGAP + tid] = sgmax[tid];
  }
}

// ---- kernel 3: parallel gap-partial merge. grid (NGAP, NBATCH), 64 thr. ----
// Block (g,b) reduces nbx slots for one gap — fixes the single-CU latency wall
// that made the fused merge cost 49 us (R11 post-mortem).
__global__ __launch_bounds__(64) void k_merge(const unsigned* __restrict__ pgmin,
                                              const unsigned* __restrict__ pgmax,
                                              unsigned* __restrict__ mgmin,  // [NBATCH*NGAP]
                                              unsigned* __restrict__ mgmax,
                                              int nbx) {
  const int g = blockIdx.x, b = blockIdx.y, tid = threadIdx.x;
  unsigned mn = INF_BITS, mx = 0u;
  for (int k = tid; k < nbx; k += 64) {
    mn = min(mn, pgmin[(b * nbx + k) * NGAP + g]);
    mx = max(mx, pgmax[(b * nbx + k) * NGAP + g]);
  }
#pragma unroll
  for (int off = 32; off > 0; off >>= 1) {
    mn = min(mn, (unsigned)__shfl_down((int)mn, off));
    mx = max(mx, (unsigned)__shfl_down((int)mx, off));
  }
  if (tid == 0) { mgmin[b * NGAP + g] = mn; mgmax[b * NGAP + g] = mx; }
}

// ---- kernel 4: final combine. 1 block, 512 thr, reads ~11 KB. --------------
__global__ __launch_bounds__(512) void k_final(const float* __restrict__ bn,
                                               const float4* __restrict__ pacc,
                                               const float* __restrict__ pcsum,
                                               const unsigned* __restrict__ mgmin,
                                               const unsigned* __restrict__ mgmax,
                                               int nbx,
                                               float* __restrict__ out) {
  const int tid = threadIdx.x;
  __shared__ double wacc[8][4];
  __shared__ unsigned smgmin[NBATCH * NGAP], smgmax[NBATCH * NGAP];
  __shared__ double sc[512];
  __shared__ float sred[512];

  // A: merge stats partials (300 float4 -> doubles)
  double a0 = 0, a1 = 0, a2 = 0, a3 = 0;
  if (tid < NBATCH * SBX) {
    const float4 p = pacc[tid];
    a0 = p.x; a1 = p.y; a2 = p.z; a3 = p.w;
  }
#pragma unroll
  for (int off = 32; off > 0; off >>= 1) {
    a0 += __shfl_down(a0, off); a1 += __shfl_down(a1, off);
    a2 += __shfl_down(a2, off); a3 += __shfl_down(a3, off);
  }
  if ((tid & 63) == 0) {
    wacc[tid >> 6][0] = a0; wacc[tid >> 6][1] = a1;
    wacc[tid >> 6][2] = a2; wacc[tid >> 6][3] = a3;
  }
  // B: load merged gap min/max (4 KB, coalesced)
  for (int o = tid; o < NBATCH * NGAP; o += 512) {
    smgmin[o] = mgmin[o]; smgmax[o] = mgmax[o];
  }
  // C: tree-reduce chamfer csums per batch (nbx is a power of 2)
  sc[tid] = (tid < NBATCH * nbx) ? (double)pcsum[tid] : 0.0;
  __syncthreads();
  for (int s = nbx >> 1; s > 0; s >>= 1) {
    if (tid < NBATCH * nbx && (tid & (nbx - 1)) < s) sc[tid] += sc[tid + s];
    __syncthreads();
  }

  // D: b->t via gap scan (bin never falls strictly inside a gap's pixel range)
  const int b = tid >> 7, j = tid & 127;
  const float bnj = bn[b * NB + j];
  float md = INFINITY;
  for (int g = 0; g < NGAP; ++g) {
    const float gmn = __uint_as_float(smgmin[b * NGAP + g]);
    const float gmx = __uint_as_float(smgmax[b * NGAP + g]);
    const float d = fmaxf(fmaxf(gmn - bnj, bnj - gmx), 0.0f);
    md = fminf(md, d * d);
  }
  sred[tid] = isfinite(md) ? md : 0.0f;   // rows with min==inf contribute 0
  __syncthreads();
  for (int s = 64; s > 0; s >>= 1) {
    if (j < s) sred[tid] += sred[tid + s];
    __syncthreads();
  }
  if (tid == 0) {
    double n = 0, sdv = 0, sd2v = 0, sl2v = 0;
#pragma unroll
    for (int w = 0; w < 8; ++w) {
      n += wacc[w][0]; sdv += wacc[w][1]; sd2v += wacc[w][2]; sl2v += wacc[w][3];
    }
    const double mean_d = sdv / n, mean_d2 = sd2v / n;
    const double silog = 10.0 * sqrt(mean_d2 - 0.85 * mean_d * mean_d);
    const double l2 = sqrt(sl2v / n);
    double ch = 0.0;
    for (int bb = 0; bb < NBATCH; ++bb)
      ch += sc[bb * nbx] + (double)sred[bb * 128];
    ch /= (double)NBATCH;
    out[0] = (float)(l2 + silog + ch);
  }
}

extern "C" void kernel_launch(void* const* d_in, const int* in_sizes, int n_in,
                              void* d_out, int out_size, void* d_ws, size_t ws_size,
                              hipStream_t stream) {
  const float* pred = (const float*)d_in[0];
  const float* targ = (const float*)d_in[1];
  const float* bins = (const float*)d_in[2];
  const void*  mask = d_in[3];
  float* out = (float*)d_out;

  // Workspace layout:
  char* w = (char*)d_ws;
  float*    bn    = (float*)w;                    // 2048 B
  float4*   pacc  = (float4*)(w + 2048);          // 4800 B -> 6848
  float*    ptmax = (float*)(w + 6848);           // 1200 B -> 8048 (pad 8064)
  unsigned* mgmin = (unsigned*)(w + 8064);        // 2064 B -> 10128
  unsigned* mgmax = (unsigned*)(w + 10128);       // 2064 B -> 12192 (pad 12288)
  const size_t hdr = 12288;
  auto need = [&](size_t nb) {
    return hdr + NBATCH * nb * sizeof(float) +
           2 * NBATCH * nb * NGAP * sizeof(unsigned);
  };
  // chamfer blocks per batch: 512 blocks total = 2 blocks/CU (8 waves/CU)
  // hides the dependent-LDS binary-search latency. Fallback for small ws.
  int nbx = 128;
  if (ws_size < need(128)) nbx = (ws_size >= need(16)) ? 16 : 4;
  float*    pcsum = (float*)(w + hdr);
  unsigned* pgmin = (unsigned*)(w + hdr + NBATCH * nbx * sizeof(float));
  unsigned* pgmax = pgmin + NBATCH * (size_t)nbx * NGAP;

  k_stats<<<dim3(SBX, NBATCH), dim3(256), 0, stream>>>(pred, targ, mask, bins,
                                                       bn, pacc, ptmax);
  k_chamfer<<<dim3(nbx, NBATCH), dim3(256), 0, stream>>>(targ, mask, bn, ptmax,
                                                         pcsum, pgmin, pgmax, nbx);
  k_merge<<<dim3(NGAP, NBATCH), dim3(64), 0, stream>>>(pgmin, pgmax,
                                                       mgmin, mgmax, nbx);
  k_final<<<dim3(1), dim3(512), 0, stream>>>(bn, pacc, pcsum, mgmin, mgmax,
                                             nbx, out);
}